// Round 1
// baseline (139.155 us; speedup 1.0000x reference)
//
#include <hip/hip_runtime.h>
#include <math.h>

namespace {

constexpr int A = 4;
constexpr int H = 2048;
constexpr int BLK = 256;            // threads per block; each owns H/BLK = 8 floats (2x float4)
constexpr float EPSV = 1e-6f;
constexpr float CLIPV = 120.0f;

__device__ __forceinline__ float clipv(float v) {
    return fminf(fmaxf(v, -CLIPV), CLIPV);
}

__global__ __launch_bounds__(BLK) void altup_fused(
    const float* __restrict__ hs,        // [A,T,H]
    const float* __restrict__ act,       // [T,H]
    const float* __restrict__ rnw,       // [H]
    const float* __restrict__ w_router,  // [A,H]
    const float* __restrict__ w_pred,    // [A*A, A] = [16,4]
    const float* __restrict__ w_corr,    // [A,A]
    const float* __restrict__ oscale,    // [H]
    float* __restrict__ out,             // corrected [A,T,H] then output [T,H]
    int T)
{
    const int t   = blockIdx.x;
    const int tid = threadIdx.x;
    const size_t TH = (size_t)T * H;
    const size_t rowOff = (size_t)t * H;

    // ---- phase 1: load x0 = hs[0,t,:], act[t,:]; accumulate 10 partial sums ----
    // part[0] = sum x0^2 ; part[1..4] = sum x0*rnw*w_router[j]
    // part[5] = sum a^2  ; part[6..9] = sum a*rnw*w_router[j]
    float x0[2][4], av[2][4];
    float part[10];
#pragma unroll
    for (int i = 0; i < 10; ++i) part[i] = 0.f;

#pragma unroll
    for (int c = 0; c < 2; ++c) {
        const int h = c * 1024 + tid * 4;
        const float4 xv = *(const float4*)(hs + rowOff + h);
        const float4 avv = *(const float4*)(act + rowOff + h);
        const float4 rv = *(const float4*)(rnw + h);
        const float4 w0 = *(const float4*)(w_router + 0 * H + h);
        const float4 w1 = *(const float4*)(w_router + 1 * H + h);
        const float4 w2 = *(const float4*)(w_router + 2 * H + h);
        const float4 w3 = *(const float4*)(w_router + 3 * H + h);
        const float xs[4] = {xv.x, xv.y, xv.z, xv.w};
        const float as[4] = {avv.x, avv.y, avv.z, avv.w};
        const float rs[4] = {rv.x, rv.y, rv.z, rv.w};
        const float ws0[4] = {w0.x, w0.y, w0.z, w0.w};
        const float ws1[4] = {w1.x, w1.y, w1.z, w1.w};
        const float ws2[4] = {w2.x, w2.y, w2.z, w2.w};
        const float ws3[4] = {w3.x, w3.y, w3.z, w3.w};
#pragma unroll
        for (int k = 0; k < 4; ++k) {
            const float x = xs[k], a = as[k], r = rs[k];
            x0[c][k] = x;
            av[c][k] = a;
            part[0] = fmaf(x, x, part[0]);
            part[5] = fmaf(a, a, part[5]);
            const float xr = x * r;
            const float ar = a * r;
            part[1] = fmaf(xr, ws0[k], part[1]);
            part[2] = fmaf(xr, ws1[k], part[2]);
            part[3] = fmaf(xr, ws2[k], part[3]);
            part[4] = fmaf(xr, ws3[k], part[4]);
            part[6] = fmaf(ar, ws0[k], part[6]);
            part[7] = fmaf(ar, ws1[k], part[7]);
            part[8] = fmaf(ar, ws2[k], part[8]);
            part[9] = fmaf(ar, ws3[k], part[9]);
        }
    }

    // ---- wave(64) shuffle reduce, then combine 4 waves via LDS ----
#pragma unroll
    for (int off = 32; off >= 1; off >>= 1) {
#pragma unroll
        for (int i = 0; i < 10; ++i) part[i] += __shfl_down(part[i], off, 64);
    }

    __shared__ float red[BLK / 64][10];
    const int wave = tid >> 6;
    const int lane = tid & 63;
    if (lane == 0) {
#pragma unroll
        for (int i = 0; i < 10; ++i) red[wave][i] = part[i];
    }
    __syncthreads();

    float sums[10];
#pragma unroll
    for (int i = 0; i < 10; ++i)
        sums[i] = red[0][i] + red[1][i] + red[2][i] + red[3][i];

    // ---- phase 2: scalar coefficients (computed redundantly per thread) ----
    const float invH = 1.0f / (float)H;
    const float sp = rsqrtf(sums[0] * invH + EPSV) * invH;  // pred: rsqrt(var+eps)/H
    const float sc = rsqrtf(sums[5] * invH + EPSV) * invH;  // corr
    float mp[4], mc[4];
#pragma unroll
    for (int j = 0; j < 4; ++j) {
        mp[j] = tanhf(sums[1 + j] * sp);
        mc[j] = tanhf(sums[6 + j] * sc);
    }

    // coef[a][b] = sum_j mp[j] * clip(w_pred[b*4+a, j])   (reshape+transpose folded)
    float coef[4][4];
#pragma unroll
    for (int b = 0; b < 4; ++b) {
#pragma unroll
        for (int a = 0; a < 4; ++a) {
            float s = 0.f;
#pragma unroll
            for (int j = 0; j < 4; ++j)
                s = fmaf(mp[j], clipv(w_pred[(b * 4 + a) * A + j]), s);
            coef[a][b] = s;
        }
    }
    // cc[a] = 1 + sum_j mc[j] * clip(w_corr[a,j])
    float cc[4];
#pragma unroll
    for (int a = 0; a < 4; ++a) {
        float s = 1.0f;
#pragma unroll
        for (int j = 0; j < 4; ++j)
            s = fmaf(mc[j], clipv(w_corr[a * A + j]), s);
        cc[a] = s;
    }

    // ---- phase 3: pointwise predict/correct/scale, fully fused ----
#pragma unroll
    for (int c = 0; c < 2; ++c) {
        const int h = c * 1024 + tid * 4;
        const float4 x1v = *(const float4*)(hs + 1 * TH + rowOff + h);
        const float4 x2v = *(const float4*)(hs + 2 * TH + rowOff + h);
        const float4 x3v = *(const float4*)(hs + 3 * TH + rowOff + h);
        const float4 sv  = *(const float4*)(oscale + h);
        const float x1[4] = {x1v.x, x1v.y, x1v.z, x1v.w};
        const float x2[4] = {x2v.x, x2v.y, x2v.z, x2v.w};
        const float x3[4] = {x3v.x, x3v.y, x3v.z, x3v.w};
        const float ss[4] = {sv.x, sv.y, sv.z, sv.w};

        float co[4][4];   // [a][k]
        float oo[4];
#pragma unroll
        for (int k = 0; k < 4; ++k) {
            const float xs4[4] = {x0[c][k], x1[k], x2[k], x3[k]};
            float pr[4];
#pragma unroll
            for (int b = 0; b < 4; ++b) {
                float s = xs4[b];
#pragma unroll
                for (int a = 0; a < 4; ++a)
                    s = fmaf(xs4[a], coef[a][b], s);
                pr[b] = s;
            }
            const float innov = av[c][k] - pr[0];
#pragma unroll
            for (int a = 0; a < 4; ++a)
                co[a][k] = fmaf(innov, cc[a], pr[a]);
            oo[k] = co[0][k] * ss[k];
        }

#pragma unroll
        for (int a = 0; a < 4; ++a) {
            float4 v;
            v.x = co[a][0]; v.y = co[a][1]; v.z = co[a][2]; v.w = co[a][3];
            *(float4*)(out + (size_t)a * TH + rowOff + h) = v;
        }
        float4 ov;
        ov.x = oo[0]; ov.y = oo[1]; ov.z = oo[2]; ov.w = oo[3];
        *(float4*)(out + (size_t)A * TH + rowOff + h) = ov;
    }
}

}  // namespace

extern "C" void kernel_launch(void* const* d_in, const int* in_sizes, int n_in,
                              void* d_out, int out_size, void* d_ws, size_t ws_size,
                              hipStream_t stream) {
    const float* hs       = (const float*)d_in[0];  // [A,T,H]
    const float* act      = (const float*)d_in[1];  // [T,H]
    const float* rnw      = (const float*)d_in[2];  // [H]
    const float* w_router = (const float*)d_in[3];  // [A,H]
    const float* w_pred   = (const float*)d_in[4];  // [16,4]
    const float* w_corr   = (const float*)d_in[5];  // [4,4]
    const float* oscale   = (const float*)d_in[6];  // [H]
    float* out = (float*)d_out;

    const int T = in_sizes[1] / H;  // activated is [T,H]

    altup_fused<<<dim3(T), dim3(BLK), 0, stream>>>(
        hs, act, rnw, w_router, w_pred, w_corr, oscale, out, T);
}

// Round 2
// 126.611 us; speedup vs baseline: 1.0991x; 1.0991x over previous
//
#include <hip/hip_runtime.h>
#include <math.h>

namespace {

typedef float f32x4 __attribute__((ext_vector_type(4)));

constexpr int A = 4;
constexpr int H = 2048;
constexpr int BLK = 256;            // each thread owns 8 floats = 2x float4 chunks
constexpr float EPSV = 1e-6f;
constexpr float CLIPV = 120.0f;

__device__ __forceinline__ float clipv(float v) {
    return fminf(fmaxf(v, -CLIPV), CLIPV);
}

__global__ __launch_bounds__(BLK) void altup_fused(
    const float* __restrict__ hs,        // [A,T,H]
    const float* __restrict__ act,       // [T,H]
    const float* __restrict__ rnw,       // [H]
    const float* __restrict__ w_router,  // [A,H]
    const float* __restrict__ w_pred,    // [16,4]
    const float* __restrict__ w_corr,    // [4,4]
    const float* __restrict__ oscale,    // [H]
    float* __restrict__ out,             // corrected [A,T,H] ++ output [T,H]
    int T)
{
    const int t   = blockIdx.x;
    const int tid = threadIdx.x;
    const size_t TH = (size_t)T * H;
    const size_t rowOff = (size_t)t * H;
    const int hofs[2] = {tid * 4, 1024 + tid * 4};

    // ---- issue ALL big-stream loads up front (read-once -> non-temporal) ----
    // Phase-3 data (x1..x3, oscale) is loaded BEFORE the reduction barrier so
    // the HBM pipe stays busy through the shuffle/tanh compute bubble.
    f32x4 x0[2], av[2], x1[2], x2[2], x3[2], rv[2], sv[2], wr[4][2];
#pragma unroll
    for (int c = 0; c < 2; ++c) {
        const int h = hofs[c];
        x0[c] = __builtin_nontemporal_load((const f32x4*)(hs + rowOff + h));
        av[c] = __builtin_nontemporal_load((const f32x4*)(act + rowOff + h));
        x1[c] = __builtin_nontemporal_load((const f32x4*)(hs + 1 * TH + rowOff + h));
        x2[c] = __builtin_nontemporal_load((const f32x4*)(hs + 2 * TH + rowOff + h));
        x3[c] = __builtin_nontemporal_load((const f32x4*)(hs + 3 * TH + rowOff + h));
        // block-shared small arrays: normal cached loads (L1/L2-resident)
        rv[c] = *(const f32x4*)(rnw + h);
        sv[c] = *(const f32x4*)(oscale + h);
#pragma unroll
        for (int j = 0; j < 4; ++j)
            wr[j][c] = *(const f32x4*)(w_router + j * H + h);
    }

    // ---- phase 1: 10 partial sums ----
    // part[0]=sum x0^2, part[1..4]=sum x0*rnw*wr[j], part[5]=sum a^2, part[6..9]=sum a*rnw*wr[j]
    float part[10];
#pragma unroll
    for (int i = 0; i < 10; ++i) part[i] = 0.f;

#pragma unroll
    for (int c = 0; c < 2; ++c) {
#pragma unroll
        for (int k = 0; k < 4; ++k) {
            const float x = x0[c][k], a = av[c][k], r = rv[c][k];
            part[0] = fmaf(x, x, part[0]);
            part[5] = fmaf(a, a, part[5]);
            const float xr = x * r;
            const float ar = a * r;
            part[1] = fmaf(xr, wr[0][c][k], part[1]);
            part[2] = fmaf(xr, wr[1][c][k], part[2]);
            part[3] = fmaf(xr, wr[2][c][k], part[3]);
            part[4] = fmaf(xr, wr[3][c][k], part[4]);
            part[6] = fmaf(ar, wr[0][c][k], part[6]);
            part[7] = fmaf(ar, wr[1][c][k], part[7]);
            part[8] = fmaf(ar, wr[2][c][k], part[8]);
            part[9] = fmaf(ar, wr[3][c][k], part[9]);
        }
    }

    // ---- wave(64) shuffle reduce + 4-wave LDS combine ----
#pragma unroll
    for (int off = 32; off >= 1; off >>= 1) {
#pragma unroll
        for (int i = 0; i < 10; ++i) part[i] += __shfl_down(part[i], off, 64);
    }

    __shared__ float red[BLK / 64][10];
    const int wave = tid >> 6;
    const int lane = tid & 63;
    if (lane == 0) {
#pragma unroll
        for (int i = 0; i < 10; ++i) red[wave][i] = part[i];
    }
    __syncthreads();

    float sums[10];
#pragma unroll
    for (int i = 0; i < 10; ++i)
        sums[i] = red[0][i] + red[1][i] + red[2][i] + red[3][i];

    // ---- phase 2: scalar coefficients (redundant per thread) ----
    const float invH = 1.0f / (float)H;
    const float sp = rsqrtf(sums[0] * invH + EPSV) * invH;
    const float sc = rsqrtf(sums[5] * invH + EPSV) * invH;
    float mp[4], mc[4];
#pragma unroll
    for (int j = 0; j < 4; ++j) {
        mp[j] = tanhf(sums[1 + j] * sp);
        mc[j] = tanhf(sums[6 + j] * sc);
    }

    // coef[a][b] = sum_j mp[j]*clip(w_pred[b*4+a, j])  (reshape+transpose folded)
    float coef[4][4];
#pragma unroll
    for (int b = 0; b < 4; ++b) {
#pragma unroll
        for (int a = 0; a < 4; ++a) {
            float s = 0.f;
#pragma unroll
            for (int j = 0; j < 4; ++j)
                s = fmaf(mp[j], clipv(w_pred[(b * 4 + a) * A + j]), s);
            coef[a][b] = s;
        }
    }
    float cc[4];
#pragma unroll
    for (int a = 0; a < 4; ++a) {
        float s = 1.0f;
#pragma unroll
        for (int j = 0; j < 4; ++j)
            s = fmaf(mc[j], clipv(w_corr[a * A + j]), s);
        cc[a] = s;
    }

    // ---- phase 3: pointwise predict/correct/scale; non-temporal stores ----
#pragma unroll
    for (int c = 0; c < 2; ++c) {
        const int h = hofs[c];
        f32x4 co[4], ov;
#pragma unroll
        for (int k = 0; k < 4; ++k) {
            const float xs4[4] = {x0[c][k], x1[c][k], x2[c][k], x3[c][k]};
            float pr[4];
#pragma unroll
            for (int b = 0; b < 4; ++b) {
                float s = xs4[b];
#pragma unroll
                for (int a = 0; a < 4; ++a)
                    s = fmaf(xs4[a], coef[a][b], s);
                pr[b] = s;
            }
            const float innov = av[c][k] - pr[0];
#pragma unroll
            for (int a = 0; a < 4; ++a)
                co[a][k] = fmaf(innov, cc[a], pr[a]);
            ov[k] = co[0][k] * sv[c][k];
        }
#pragma unroll
        for (int a = 0; a < 4; ++a)
            __builtin_nontemporal_store(co[a], (f32x4*)(out + (size_t)a * TH + rowOff + h));
        __builtin_nontemporal_store(ov, (f32x4*)(out + (size_t)A * TH + rowOff + h));
    }
}

}  // namespace

extern "C" void kernel_launch(void* const* d_in, const int* in_sizes, int n_in,
                              void* d_out, int out_size, void* d_ws, size_t ws_size,
                              hipStream_t stream) {
    const float* hs       = (const float*)d_in[0];
    const float* act      = (const float*)d_in[1];
    const float* rnw      = (const float*)d_in[2];
    const float* w_router = (const float*)d_in[3];
    const float* w_pred   = (const float*)d_in[4];
    const float* w_corr   = (const float*)d_in[5];
    const float* oscale   = (const float*)d_in[6];
    float* out = (float*)d_out;

    const int T = in_sizes[1] / H;  // activated is [T,H]

    altup_fused<<<dim3(T), dim3(BLK), 0, stream>>>(
        hs, act, rnw, w_router, w_pred, w_corr, oscale, out, T);
}